// Round 2
// 767.018 us; speedup vs baseline: 1.0448x; 1.0448x over previous
//
#include <hip/hip_runtime.h>

typedef unsigned short ushort_t;
typedef __attribute__((ext_vector_type(8))) unsigned short ushortx8;
typedef __attribute__((ext_vector_type(8))) __bf16 bf16x8;
typedef __attribute__((ext_vector_type(4))) float floatx4;

// ---------- problem constants ----------
#define NE 8
#define NT 16384
#define ND 1024
#define NF 4096
#define MPE (NT / NE)   // 2048 tokens per expert

// ---------- helpers ----------
__device__ __forceinline__ float b2f(ushort_t x) {
    unsigned u = ((unsigned)x) << 16;
    float f;
    __builtin_memcpy(&f, &u, 4);
    return f;
}
__device__ __forceinline__ ushort_t f2b(float f) {
    unsigned u;
    __builtin_memcpy(&u, &f, 4);
    u += 0x7FFFu + ((u >> 16) & 1u);   // RNE
    return (ushort_t)(u >> 16);
}
// jax.nn.gelu default = tanh approximation
__device__ __forceinline__ float gelu_tanh(float x) {
    float u = x + 0.044715f * x * x * x;
    float e = __expf(1.5957691216f * u);     // exp(2 * sqrt(2/pi) * u)
    float t = 1.0f - 2.0f / (e + 1.0f);      // tanh, inf-safe
    return 0.5f * x * (1.0f + t);
}

// ---------- dtype detector ----------
__global__ void detect_dtype(const ushort_t* __restrict__ x, int* __restrict__ flag) {
    int l = threadIdx.x;                  // 64 threads
    float v = b2f(x[2 * l]);
    float a = fabsf(v);
    int big = (a > 1e4f) || (a != a);
    unsigned long long m = __ballot(big);
    if (l == 0) *flag = (__popcll(m) >= 4) ? 1 : 0;
}

// ---------- convert (fp32|bf16) -> bf16, n multiple of 8 ----------
__global__ __launch_bounds__(256) void conv_bf16(
    const void* __restrict__ src, ushort_t* __restrict__ dst, int n,
    const int* __restrict__ flagp)
{
    int flag = *flagp;
    int i = (blockIdx.x * 256 + threadIdx.x) * 8;
    if (i >= n) return;
    if (flag) {
        const float* s = (const float*)src + i;
        ushortx8 o;
#pragma unroll
        for (int j = 0; j < 8; ++j) o[j] = f2b(s[j]);
        *(ushortx8*)(dst + i) = o;
    } else {
        *(ushortx8*)(dst + i) = *(const ushortx8*)((const ushort_t*)src + i);
    }
}

// ---------- weight transpose (fp32|bf16 src) -> bf16 dst[e][c][r] ----------
// XOR-swizzled LDS tile: 16B chunk c of row r stored at chunk c ^ ((r>>3)&7).
// Write side: contiguous 1KB per 64-lane group (BW-limited, no conflict).
// Read side (column walk): phys chunk = (oc>>3) ^ (rr>>3) varies across the
// 8 row-octet lanes -> banks chunk*4 + (oc&7)>>1 cover all 32 banks, 2
// lanes/bank in the SAME word (broadcast, free per m136). The old +8-pad
// tile collapsed column reads onto 4 banks (16-way conflict).
// grid (C/64, R/64, E), block 256
__global__ __launch_bounds__(256) void transpose_e(
    const void* __restrict__ src, ushort_t* __restrict__ dst, int R, int C,
    const int* __restrict__ flagp)
{
    __shared__ __align__(16) ushort_t tile[64 * 64];
    int flag = *flagp;
    int e = blockIdx.z;
    size_t ebase = (size_t)e * R * C;
    int r0 = blockIdx.y * 64, c0 = blockIdx.x * 64;
    int t = threadIdx.x;
#pragma unroll
    for (int i = 0; i < 2; ++i) {
        int ch = t + 256 * i;          // 0..511
        int r  = ch >> 3;              // 0..63
        int c8 = ch & 7;               // 16B chunk 0..7
        size_t gi = ebase + (size_t)(r0 + r) * C + (c0 + c8 * 8);
        ushortx8 v;
        if (flag) {
            const float* s = (const float*)src + gi;
#pragma unroll
            for (int j = 0; j < 8; ++j) v[j] = f2b(s[j]);
        } else {
            v = *(const ushortx8*)((const ushort_t*)src + gi);
        }
        *(ushortx8*)&tile[r * 64 + ((c8 ^ ((r >> 3) & 7)) * 8)] = v;
    }
    __syncthreads();
#pragma unroll
    for (int i = 0; i < 2; ++i) {
        int ch  = t + 256 * i;
        int oc  = ch >> 3;             // input col = output row
        int orr = (ch & 7) * 8;        // input row octet
        ushortx8 v;
#pragma unroll
        for (int j = 0; j < 8; ++j) {
            int rr = orr + j;
            v[j] = tile[rr * 64 + (((oc >> 3) ^ ((rr >> 3) & 7)) * 8) + (oc & 7)];
        }
        *(ushortx8*)(dst + ebase + (size_t)(c0 + oc) * R + (r0 + orr)) = v;
    }
}

// ---------- grouped GEMM, 256x256 tile, 4-phase counted-vmcnt schedule ----------
// C[e] = act(A[e] @ Bt[e]^T + bias[e]).  A: [E*Mpe][K] bf16, Bt: [E][N][K] bf16.
// 512 threads = 8 waves (2M x 4N); per-wave output 128x64; BK=64.
// LDS: double-buffered A[256][64] + B[256][64] = 128 KiB -> 1 block/CU.
// Staging: global_load_lds w=16 with the verified lane-XOR swizzle
// (phys 16B-chunk = logical ^ (row&7); reads XOR back) -> 0 bank conflicts.
// Schedule per K-tile t (4 phases, quadrant (qm=p>>1, qn=p&1)):
//   ph0: ds-reads quad(0,0) | issue A1,A3,B0,B1 of t+1 (free buf) | bar | MFMA | bar
//   ph1: ds-reads quad(0,1) | issue B2,B3 of t+1                  | bar | MFMA | bar
//   ph2: ds-reads quad(1,0) | issue A0,A2 of t+2 into CUR buf     | bar | MFMA | bar
//        (A rows [0,64)+[128,192) last read at ph1 and drained by ph1's
//         lgkmcnt(0); issue sits after ph1's closing barrier -> race-free)
//   ph3: ds-reads quad(1,1) | bar | MFMA | s_waitcnt vmcnt(2) | bar
//        (vmcnt(2) leaves exactly A0,A2 of t+2 in flight; all t+1 landed.
//         Last two tiles fall back to vmcnt(0) to drain. vmcnt can only
//         over-wait if the compiler pre-issues unrelated loads -> safe.)
// Raw s_barrier (not __syncthreads) so no compiler-forced vmcnt(0) drain.
template <int GELU, int DUALOUT>
__global__ __launch_bounds__(512, 2) void gemm_bt8(
    const ushort_t* __restrict__ A, const ushort_t* __restrict__ Bt,
    const ushort_t* __restrict__ bias, void* __restrict__ Cout,
    int Mpe, int N, int K, const int* __restrict__ flagp)
{
    __shared__ __align__(16) ushort_t sA[2][256 * 64];
    __shared__ __align__(16) ushort_t sB[2][256 * 64];

    const int flag = DUALOUT ? *flagp : 0;
    const int e  = blockIdx.z;
    const int m0 = blockIdx.y * 256;
    const int n0 = blockIdx.x * 256;
    const ushort_t* Ae = A  + (size_t)e * Mpe * K + (size_t)m0 * K;
    const ushort_t* Be = Bt + (size_t)e * N   * K + (size_t)n0 * K;

    const int t  = threadIdx.x;
    const int w  = t >> 6;         // wave 0..7
    const int l  = t & 63;
    const int wr = w >> 2;         // 0..1  (M half)
    const int wc = w & 3;          // 0..3  (N quarter)
    // staging lane roles: 8 rows x 8 chunks(16B) per instruction per wave
    const int lwr = l >> 3;        // row within the 8-row group
    const int swz = (l & 7) ^ lwr; // this lane fetches logical chunk swz
    // fragment lane roles
    const int q  = l >> 4;         // 0..3
    const int ln = l & 15;

    const int KT = K >> 6;         // K-tiles (>= 16 here)

#define STAGE(G, S, r0c, kcol) do {                                          \
        int rb_ = (r0c) + w * 8;                                             \
        const ushort_t* ga_ = (G) + (size_t)(rb_ + lwr) * K + (kcol) + swz * 8; \
        __builtin_amdgcn_global_load_lds(                                    \
            (const __attribute__((address_space(1))) void*)ga_,              \
            (__attribute__((address_space(3))) void*)&(S)[rb_ * 64], 16, 0, 0); \
    } while (0)

    floatx4 acc[8][4] = {};   // [qm*4+mi][qn*2+nj]

    // ---- prologue: tile 0 fully; A0,A2 of tile 1 stay in flight ----
    STAGE(Ae, sA[0],   0, 0); STAGE(Ae, sA[0],  64, 0);
    STAGE(Ae, sA[0], 128, 0); STAGE(Ae, sA[0], 192, 0);
    STAGE(Be, sB[0],   0, 0); STAGE(Be, sB[0],  64, 0);
    STAGE(Be, sB[0], 128, 0); STAGE(Be, sB[0], 192, 0);
    if (KT > 1) {
        STAGE(Ae, sA[1],   0, 64);
        STAGE(Ae, sA[1], 128, 64);
        asm volatile("s_waitcnt vmcnt(2)" ::: "memory");
    } else {
        asm volatile("s_waitcnt vmcnt(0)" ::: "memory");
    }
    __builtin_amdgcn_s_barrier();

    for (int kt = 0; kt < KT; ++kt) {
        const int cur = kt & 1;
        ushort_t* sAc = &sA[cur][0];
        ushort_t* sBc = &sB[cur][0];
        ushort_t* sAn = &sA[cur ^ 1][0];
        ushort_t* sBn = &sB[cur ^ 1][0];
        const int kc = kt * 64;

#pragma unroll
        for (int p = 0; p < 4; ++p) {
            const int qm = p >> 1, qn = p & 1;

            // ---- register subtile ds-reads (12 x ds_read_b128) ----
            bf16x8 af[2][4], bv[2][2];
#pragma unroll
            for (int ks = 0; ks < 2; ++ks) {
#pragma unroll
                for (int mi = 0; mi < 4; ++mi) {
                    int m = wr * 128 + qm * 64 + mi * 16 + ln;
                    af[ks][mi] = *(const bf16x8*)&sAc[m * 64 + (((ks * 4 + q) ^ (m & 7)) * 8)];
                }
#pragma unroll
                for (int nj = 0; nj < 2; ++nj) {
                    int n = wc * 64 + qn * 32 + nj * 16 + ln;
                    bv[ks][nj] = *(const bf16x8*)&sBc[n * 64 + (((ks * 4 + q) ^ (n & 7)) * 8)];
                }
            }

            // ---- staging issues for this phase ----
            if (p == 0 && kt + 1 < KT) {
                STAGE(Ae, sAn,  64, kc + 64);
                STAGE(Ae, sAn, 192, kc + 64);
                STAGE(Be, sBn,   0, kc + 64);
                STAGE(Be, sBn,  64, kc + 64);
            }
            if (p == 1 && kt + 1 < KT) {
                STAGE(Be, sBn, 128, kc + 64);
                STAGE(Be, sBn, 192, kc + 64);
            }
            if (p == 2 && kt + 2 < KT) {
                STAGE(Ae, sAc,   0, kc + 128);   // regions done since ph1
                STAGE(Ae, sAc, 128, kc + 128);
            }

            __builtin_amdgcn_s_barrier();
            asm volatile("s_waitcnt lgkmcnt(0)" ::: "memory");
            __builtin_amdgcn_sched_barrier(0);

            __builtin_amdgcn_s_setprio(1);
#pragma unroll
            for (int ks = 0; ks < 2; ++ks)
#pragma unroll
                for (int mi = 0; mi < 4; ++mi)
#pragma unroll
                    for (int nj = 0; nj < 2; ++nj)
                        acc[qm * 4 + mi][qn * 2 + nj] =
                            __builtin_amdgcn_mfma_f32_16x16x32_bf16(
                                af[ks][mi], bv[ks][nj],
                                acc[qm * 4 + mi][qn * 2 + nj], 0, 0, 0);
            __builtin_amdgcn_s_setprio(0);

            if (p == 3) {
                if (kt + 2 < KT) asm volatile("s_waitcnt vmcnt(2)" ::: "memory");
                else             asm volatile("s_waitcnt vmcnt(0)" ::: "memory");
            }
            __builtin_amdgcn_s_barrier();
        }
    }
#undef STAGE

    // ---- epilogue: C/D layout col=lane&15, row=q*4+r  [m89-verified] ----
    const ushort_t* be = bias + (size_t)e * N + n0;
#pragma unroll
    for (int qn = 0; qn < 2; ++qn) {
#pragma unroll
        for (int nj = 0; nj < 2; ++nj) {
            int col = wc * 64 + qn * 32 + nj * 16 + ln;
            float bvv = b2f(be[col]);
#pragma unroll
            for (int qm = 0; qm < 2; ++qm) {
#pragma unroll
                for (int mi = 0; mi < 4; ++mi) {
#pragma unroll
                    for (int r = 0; r < 4; ++r) {
                        int row = wr * 128 + qm * 64 + mi * 16 + q * 4 + r;
                        float v = acc[qm * 4 + mi][qn * 2 + nj][r] + bvv;
                        if (GELU) v = gelu_tanh(v);
                        size_t idx = (size_t)e * Mpe * N + (size_t)(m0 + row) * N + (n0 + col);
                        if (DUALOUT && flag) ((float*)Cout)[idx] = v;
                        else                 ((ushort_t*)Cout)[idx] = f2b(v);
                    }
                }
            }
        }
    }
}

extern "C" void kernel_launch(void* const* d_in, const int* in_sizes, int n_in,
                              void* d_out, int out_size, void* d_ws, size_t ws_size,
                              hipStream_t stream) {
    const void* x  = d_in[0];
    // d_in[1] = expert_size (uniform T/E by construction, unused)
    const void* w1 = d_in[2];
    const void* b1 = d_in[3];
    const void* w2 = d_in[4];
    const void* b2 = d_in[5];

    char* ws = (char*)d_ws;
    int*      flag = (int*)ws;                                    // @0
    ushort_t* xb   = (ushort_t*)(ws + ((size_t)1  << 20));        // 32 MB
    ushort_t* b1b  = (ushort_t*)(ws + ((size_t)34 << 20));        // 64 KB
    ushort_t* b2b  = (ushort_t*)(ws + ((size_t)35 << 20));        // 16 KB
    ushort_t* wT   = (ushort_t*)(ws + ((size_t)36 << 20));        // 64 MB (w1t, then w2t)
    ushort_t* H    = (ushort_t*)(ws + ((size_t)100 << 20));       // 128 MB -> ends 228 MB

    detect_dtype<<<1, 64, 0, stream>>>((const ushort_t*)x, flag);

    conv_bf16<<<(NT * ND / 8 + 255) / 256, 256, 0, stream>>>(x,  xb,  NT * ND, flag);
    conv_bf16<<<(NE * NF / 8 + 255) / 256, 256, 0, stream>>>(b1, b1b, NE * NF, flag);
    conv_bf16<<<(NE * ND / 8 + 255) / 256, 256, 0, stream>>>(b2, b2b, NE * ND, flag);

    // w1 [E][D][F] -> wT [E][F][D]
    transpose_e<<<dim3(NF / 64, ND / 64, NE), 256, 0, stream>>>(w1, wT, ND, NF, flag);
    // H = gelu(X @ W1 + b1)   (internal, always bf16)
    gemm_bt8<1, 0><<<dim3(NF / 256, MPE / 256, NE), 512, 0, stream>>>(
        xb, wT, b1b, H, MPE, NF, ND, flag);
    // w2 [E][F][D] -> wT [E][D][F]   (reuses wT after gemm1 is done)
    transpose_e<<<dim3(ND / 64, NF / 64, NE), 256, 0, stream>>>(w2, wT, NF, ND, flag);
    // Y = H @ W2 + b2   (output dtype follows detected input dtype)
    gemm_bt8<0, 1><<<dim3(ND / 256, MPE / 256, NE), 512, 0, stream>>>(
        H, wT, b2b, d_out, MPE, ND, NF, flag);
}

// Round 5
// 743.439 us; speedup vs baseline: 1.0779x; 1.0317x over previous
//
#include <hip/hip_runtime.h>

typedef unsigned short ushort_t;
typedef __attribute__((ext_vector_type(8))) unsigned short ushortx8;
typedef __attribute__((ext_vector_type(8))) __bf16 bf16x8;
typedef __attribute__((ext_vector_type(4))) float floatx4;

// ---------- problem constants ----------
#define NE 8
#define NT 16384
#define ND 1024
#define NF 4096
#define MPE (NT / NE)   // 2048 tokens per expert

// ---------- helpers ----------
__device__ __forceinline__ float b2f(ushort_t x) {
    unsigned u = ((unsigned)x) << 16;
    float f;
    __builtin_memcpy(&f, &u, 4);
    return f;
}
__device__ __forceinline__ ushort_t f2b(float f) {
    unsigned u;
    __builtin_memcpy(&u, &f, 4);
    u += 0x7FFFu + ((u >> 16) & 1u);   // RNE
    return (ushort_t)(u >> 16);
}
// jax.nn.gelu default = tanh approximation
__device__ __forceinline__ float gelu_tanh(float x) {
    float u = x + 0.044715f * x * x * x;
    float e = __expf(1.5957691216f * u);     // exp(2 * sqrt(2/pi) * u)
    float t = 1.0f - 2.0f / (e + 1.0f);      // tanh, inf-safe
    return 0.5f * x * (1.0f + t);
}

// ---------- dtype detector ----------
__global__ void detect_dtype(const ushort_t* __restrict__ x, int* __restrict__ flag) {
    int l = threadIdx.x;                  // 64 threads
    float v = b2f(x[2 * l]);
    float a = fabsf(v);
    int big = (a > 1e4f) || (a != a);
    unsigned long long m = __ballot(big);
    if (l == 0) *flag = (__popcll(m) >= 4) ? 1 : 0;
}

// ---------- convert (fp32|bf16) -> bf16, n multiple of 8 ----------
__global__ __launch_bounds__(256) void conv_bf16(
    const void* __restrict__ src, ushort_t* __restrict__ dst, int n,
    const int* __restrict__ flagp)
{
    int flag = *flagp;
    int i = (blockIdx.x * 256 + threadIdx.x) * 8;
    if (i >= n) return;
    if (flag) {
        const float* s = (const float*)src + i;
        ushortx8 o;
#pragma unroll
        for (int j = 0; j < 8; ++j) o[j] = f2b(s[j]);
        *(ushortx8*)(dst + i) = o;
    } else {
        *(ushortx8*)(dst + i) = *(const ushortx8*)((const ushort_t*)src + i);
    }
}

// ---------- weight transpose (fp32|bf16 src) -> bf16 dst[e][c][r] ----------
// XOR-swizzled LDS tile: 16B chunk c of row r stored at chunk c ^ ((r>>3)&7).
// grid (C/64, R/64, E), block 256
__global__ __launch_bounds__(256) void transpose_e(
    const void* __restrict__ src, ushort_t* __restrict__ dst, int R, int C,
    const int* __restrict__ flagp)
{
    __shared__ __align__(16) ushort_t tile[64 * 64];
    int flag = *flagp;
    int e = blockIdx.z;
    size_t ebase = (size_t)e * R * C;
    int r0 = blockIdx.y * 64, c0 = blockIdx.x * 64;
    int t = threadIdx.x;
#pragma unroll
    for (int i = 0; i < 2; ++i) {
        int ch = t + 256 * i;          // 0..511
        int r  = ch >> 3;              // 0..63
        int c8 = ch & 7;               // 16B chunk 0..7
        size_t gi = ebase + (size_t)(r0 + r) * C + (c0 + c8 * 8);
        ushortx8 v;
        if (flag) {
            const float* s = (const float*)src + gi;
#pragma unroll
            for (int j = 0; j < 8; ++j) v[j] = f2b(s[j]);
        } else {
            v = *(const ushortx8*)((const ushort_t*)src + gi);
        }
        *(ushortx8*)&tile[r * 64 + ((c8 ^ ((r >> 3) & 7)) * 8)] = v;
    }
    __syncthreads();
#pragma unroll
    for (int i = 0; i < 2; ++i) {
        int ch  = t + 256 * i;
        int oc  = ch >> 3;             // input col = output row
        int orr = (ch & 7) * 8;        // input row octet
        ushortx8 v;
#pragma unroll
        for (int j = 0; j < 8; ++j) {
            int rr = orr + j;
            v[j] = tile[rr * 64 + (((oc >> 3) ^ ((rr >> 3) & 7)) * 8) + (oc & 7)];
        }
        *(ushortx8*)(dst + ebase + (size_t)(c0 + oc) * R + (r0 + orr)) = v;
    }
}

// ================= GEMM variant 1: round-2-VERIFIED gemm_bt8 ===============
// (4-phase counted-vmcnt schedule; measured 238 us @ MfmaUtil 24.7%.)
// Kept verbatim as the known-good control arm of this round's bisect.
template <int GELU, int DUALOUT>
__global__ __launch_bounds__(512, 2) void gemm_bt8(
    const ushort_t* __restrict__ A, const ushort_t* __restrict__ Bt,
    const ushort_t* __restrict__ bias, void* __restrict__ Cout,
    int Mpe, int N, int K, const int* __restrict__ flagp)
{
    __shared__ __align__(16) ushort_t sA[2][256 * 64];
    __shared__ __align__(16) ushort_t sB[2][256 * 64];

    const int flag = DUALOUT ? *flagp : 0;
    const int e  = blockIdx.z;
    const int m0 = blockIdx.y * 256;
    const int n0 = blockIdx.x * 256;
    const ushort_t* Ae = A  + (size_t)e * Mpe * K + (size_t)m0 * K;
    const ushort_t* Be = Bt + (size_t)e * N   * K + (size_t)n0 * K;

    const int t  = threadIdx.x;
    const int w  = t >> 6;         // wave 0..7
    const int l  = t & 63;
    const int wr = w >> 2;         // 0..1  (M half)
    const int wc = w & 3;          // 0..3  (N quarter)
    const int lwr = l >> 3;        // row within the 8-row group
    const int swz = (l & 7) ^ lwr; // this lane fetches logical chunk swz
    const int q  = l >> 4;         // 0..3
    const int ln = l & 15;

    const int KT = K >> 6;

#define STAGE(G, S, r0c, kcol) do {                                          \
        int rb_ = (r0c) + w * 8;                                             \
        const ushort_t* ga_ = (G) + (size_t)(rb_ + lwr) * K + (kcol) + swz * 8; \
        __builtin_amdgcn_global_load_lds(                                    \
            (const __attribute__((address_space(1))) void*)ga_,              \
            (__attribute__((address_space(3))) void*)&(S)[rb_ * 64], 16, 0, 0); \
    } while (0)

    floatx4 acc[8][4] = {};   // [qm*4+mi][qn*2+nj]

    STAGE(Ae, sA[0],   0, 0); STAGE(Ae, sA[0],  64, 0);
    STAGE(Ae, sA[0], 128, 0); STAGE(Ae, sA[0], 192, 0);
    STAGE(Be, sB[0],   0, 0); STAGE(Be, sB[0],  64, 0);
    STAGE(Be, sB[0], 128, 0); STAGE(Be, sB[0], 192, 0);
    if (KT > 1) {
        STAGE(Ae, sA[1],   0, 64);
        STAGE(Ae, sA[1], 128, 64);
        asm volatile("s_waitcnt vmcnt(2)" ::: "memory");
    } else {
        asm volatile("s_waitcnt vmcnt(0)" ::: "memory");
    }
    __builtin_amdgcn_s_barrier();

    for (int kt = 0; kt < KT; ++kt) {
        const int cur = kt & 1;
        ushort_t* sAc = &sA[cur][0];
        ushort_t* sBc = &sB[cur][0];
        ushort_t* sAn = &sA[cur ^ 1][0];
        ushort_t* sBn = &sB[cur ^ 1][0];
        const int kc = kt * 64;

#pragma unroll
        for (int p = 0; p < 4; ++p) {
            const int qm = p >> 1, qn = p & 1;

            bf16x8 af[2][4], bv[2][2];
#pragma unroll
            for (int ks = 0; ks < 2; ++ks) {
#pragma unroll
                for (int mi = 0; mi < 4; ++mi) {
                    int m = wr * 128 + qm * 64 + mi * 16 + ln;
                    af[ks][mi] = *(const bf16x8*)&sAc[m * 64 + (((ks * 4 + q) ^ (m & 7)) * 8)];
                }
#pragma unroll
                for (int nj = 0; nj < 2; ++nj) {
                    int n = wc * 64 + qn * 32 + nj * 16 + ln;
                    bv[ks][nj] = *(const bf16x8*)&sBc[n * 64 + (((ks * 4 + q) ^ (n & 7)) * 8)];
                }
            }

            if (p == 0 && kt + 1 < KT) {
                STAGE(Ae, sAn,  64, kc + 64);
                STAGE(Ae, sAn, 192, kc + 64);
                STAGE(Be, sBn,   0, kc + 64);
                STAGE(Be, sBn,  64, kc + 64);
            }
            if (p == 1 && kt + 1 < KT) {
                STAGE(Be, sBn, 128, kc + 64);
                STAGE(Be, sBn, 192, kc + 64);
            }
            if (p == 2 && kt + 2 < KT) {
                STAGE(Ae, sAc,   0, kc + 128);
                STAGE(Ae, sAc, 128, kc + 128);
            }

            __builtin_amdgcn_s_barrier();
            asm volatile("s_waitcnt lgkmcnt(0)" ::: "memory");
            __builtin_amdgcn_sched_barrier(0);

            __builtin_amdgcn_s_setprio(1);
#pragma unroll
            for (int ks = 0; ks < 2; ++ks)
#pragma unroll
                for (int mi = 0; mi < 4; ++mi)
#pragma unroll
                    for (int nj = 0; nj < 2; ++nj)
                        acc[qm * 4 + mi][qn * 2 + nj] =
                            __builtin_amdgcn_mfma_f32_16x16x32_bf16(
                                af[ks][mi], bv[ks][nj],
                                acc[qm * 4 + mi][qn * 2 + nj], 0, 0, 0);
            __builtin_amdgcn_s_setprio(0);

            if (p == 3) {
                if (kt + 2 < KT) asm volatile("s_waitcnt vmcnt(2)" ::: "memory");
                else             asm volatile("s_waitcnt vmcnt(0)" ::: "memory");
            }
            __builtin_amdgcn_s_barrier();
        }
    }
#undef STAGE

    const ushort_t* be = bias + (size_t)e * N + n0;
#pragma unroll
    for (int qn = 0; qn < 2; ++qn) {
#pragma unroll
        for (int nj = 0; nj < 2; ++nj) {
            int col = wc * 64 + qn * 32 + nj * 16 + ln;
            float bvv = b2f(be[col]);
#pragma unroll
            for (int qm = 0; qm < 2; ++qm) {
#pragma unroll
                for (int mi = 0; mi < 4; ++mi) {
#pragma unroll
                    for (int r = 0; r < 4; ++r) {
                        int row = wr * 128 + qm * 64 + mi * 16 + q * 4 + r;
                        float v = acc[qm * 4 + mi][qn * 2 + nj][r] + bvv;
                        if (GELU) v = gelu_tanh(v);
                        size_t idx = (size_t)e * Mpe * N + (size_t)(m0 + row) * N + (n0 + col);
                        if (DUALOUT && flag) ((float*)Cout)[idx] = v;
                        else                 ((ushort_t*)Cout)[idx] = f2b(v);
                    }
                }
            }
        }
    }
}

// ================= GEMM variant 2: min-LDS-read Gray schedule ==============
// Under test in this round's bisect (gemm2 slot only). Each fragment read
// ONCE per K-tile (24 ds_read_b128/wave), MFMA in Gray-quadrant order,
// ONE __syncthreads per K-tile, XCD-aware bijective block swizzle.
template <int GELU, int DUALOUT>
__global__ __launch_bounds__(512, 2) void gemm_g2(
    const ushort_t* __restrict__ A, const ushort_t* __restrict__ Bt,
    const ushort_t* __restrict__ bias, void* __restrict__ Cout,
    int Mpe, int N, int K, const int* __restrict__ flagp)
{
    __shared__ __align__(16) ushort_t sA[2][256 * 64];
    __shared__ __align__(16) ushort_t sB[2][256 * 64];

    const int flag = DUALOUT ? *flagp : 0;

    const unsigned gx = gridDim.x, gy = gridDim.y;
    unsigned bid = blockIdx.x + gx * (blockIdx.y + gy * blockIdx.z);
    unsigned nwg = gx * gy * gridDim.z;
    unsigned cpx = nwg >> 3;
    unsigned sw  = (bid & 7) * cpx + (bid >> 3);
    unsigned lx = __ffs(gx) - 1, ly = __ffs(gy) - 1;   // dims are pow2
    const int e  = sw >> (lx + ly);
    const int m0 = ((sw >> lx) & (gy - 1)) * 256;
    const int n0 = (sw & (gx - 1)) * 256;

    const ushort_t* Ae = A  + (size_t)e * Mpe * K + (size_t)m0 * K;
    const ushort_t* Be = Bt + (size_t)e * N   * K + (size_t)n0 * K;

    const int t  = threadIdx.x;
    const int w  = t >> 6;         // wave 0..7
    const int l  = t & 63;
    const int wr = w >> 2;         // 0..1  (M half)
    const int wc = w & 3;          // 0..3  (N quarter)
    const int lwr = l >> 3;
    const int swz = (l & 7) ^ lwr;
    const int q  = l >> 4;
    const int ln = l & 15;

    const int KT = K >> 6;         // even (16 or 64 here)

#define STAGE(G, S, r0c, kcol) do {                                          \
        int rb_ = (r0c) + w * 8;                                             \
        const ushort_t* ga_ = (G) + (size_t)(rb_ + lwr) * K + (kcol) + swz * 8; \
        __builtin_amdgcn_global_load_lds(                                    \
            (const __attribute__((address_space(1))) void*)ga_,              \
            (__attribute__((address_space(3))) void*)&(S)[rb_ * 64], 16, 0, 0); \
    } while (0)

#define STAGE8(AT, BT, kcol) do {                                            \
        STAGE(Ae, AT,   0, kcol); STAGE(Ae, AT,  64, kcol);                  \
        STAGE(Ae, AT, 128, kcol); STAGE(Ae, AT, 192, kcol);                  \
        STAGE(Be, BT,   0, kcol); STAGE(Be, BT,  64, kcol);                  \
        STAGE(Be, BT, 128, kcol); STAGE(Be, BT, 192, kcol);                  \
    } while (0)

    floatx4 acc[8][4] = {};   // [qm*4+mi][qn*2+nj]

#define KSTEP(SAc, SBc, SAn, SBn, kcn, PRE) do {                             \
        if (PRE) { STAGE8(SAn, SBn, kcn); }                                  \
        bf16x8 a0[2][4], a1[2][4], b0[2][2], b1[2][2];                       \
        _Pragma("unroll")                                                    \
        for (int ks = 0; ks < 2; ++ks) {                                     \
            _Pragma("unroll")                                                \
            for (int mi = 0; mi < 4; ++mi) {                                 \
                int m  = wr * 128 + mi * 16 + ln;                            \
                int m2 = m + 64;                                             \
                a0[ks][mi] = *(const bf16x8*)&(SAc)[m  * 64 + (((ks * 4 + q) ^ (m  & 7)) * 8)]; \
                a1[ks][mi] = *(const bf16x8*)&(SAc)[m2 * 64 + (((ks * 4 + q) ^ (m2 & 7)) * 8)]; \
            }                                                                \
            _Pragma("unroll")                                                \
            for (int nj = 0; nj < 2; ++nj) {                                 \
                int n  = wc * 64 + nj * 16 + ln;                             \
                int n2 = n + 32;                                             \
                b0[ks][nj] = *(const bf16x8*)&(SBc)[n  * 64 + (((ks * 4 + q) ^ (n  & 7)) * 8)]; \
                b1[ks][nj] = *(const bf16x8*)&(SBc)[n2 * 64 + (((ks * 4 + q) ^ (n2 & 7)) * 8)]; \
            }                                                                \
        }                                                                    \
        _Pragma("unroll")                                                    \
        for (int ks = 0; ks < 2; ++ks)  /* G0 */                             \
            _Pragma("unroll")                                                \
            for (int mi = 0; mi < 4; ++mi)                                   \
                _Pragma("unroll")                                            \
                for (int nj = 0; nj < 2; ++nj)                               \
                    acc[mi][nj] = __builtin_amdgcn_mfma_f32_16x16x32_bf16(   \
                        a0[ks][mi], b0[ks][nj], acc[mi][nj], 0, 0, 0);       \
        _Pragma("unroll")                                                    \
        for (int ks = 0; ks < 2; ++ks)  /* G1 */                             \
            _Pragma("unroll")                                                \
            for (int mi = 0; mi < 4; ++mi)                                   \
                _Pragma("unroll")                                            \
                for (int nj = 0; nj < 2; ++nj)                               \
                    acc[mi][2 + nj] = __builtin_amdgcn_mfma_f32_16x16x32_bf16( \
                        a0[ks][mi], b1[ks][nj], acc[mi][2 + nj], 0, 0, 0);   \
        _Pragma("unroll")                                                    \
        for (int ks = 0; ks < 2; ++ks)  /* G2 */                             \
            _Pragma("unroll")                                                \
            for (int mi = 0; mi < 4; ++mi)                                   \
                _Pragma("unroll")                                            \
                for (int nj = 0; nj < 2; ++nj)                               \
                    acc[4 + mi][2 + nj] = __builtin_amdgcn_mfma_f32_16x16x32_bf16( \
                        a1[ks][mi], b1[ks][nj], acc[4 + mi][2 + nj], 0, 0, 0); \
        _Pragma("unroll")                                                    \
        for (int ks = 0; ks < 2; ++ks)  /* G3 */                             \
            _Pragma("unroll")                                                \
            for (int mi = 0; mi < 4; ++mi)                                   \
                _Pragma("unroll")                                            \
                for (int nj = 0; nj < 2; ++nj)                               \
                    acc[4 + mi][nj] = __builtin_amdgcn_mfma_f32_16x16x32_bf16( \
                        a1[ks][mi], b0[ks][nj], acc[4 + mi][nj], 0, 0, 0);   \
        __syncthreads();                                                     \
    } while (0)

    STAGE8(sA[0], sB[0], 0);
    __syncthreads();

    for (int kt = 0; kt < KT; kt += 2) {
        const int kc = kt * 64;
        KSTEP(sA[0], sB[0], sA[1], sB[1], kc + 64,  true);
        KSTEP(sA[1], sB[1], sA[0], sB[0], kc + 128, (kt + 2 < KT));
    }
#undef KSTEP
#undef STAGE8
#undef STAGE

    const ushort_t* be = bias + (size_t)e * N + n0;
#pragma unroll
    for (int qn = 0; qn < 2; ++qn) {
#pragma unroll
        for (int nj = 0; nj < 2; ++nj) {
            int col = wc * 64 + qn * 32 + nj * 16 + ln;
            float bvv = b2f(be[col]);
#pragma unroll
            for (int qm = 0; qm < 2; ++qm) {
#pragma unroll
                for (int mi = 0; mi < 4; ++mi) {
#pragma unroll
                    for (int r = 0; r < 4; ++r) {
                        int row = wr * 128 + qm * 64 + mi * 16 + q * 4 + r;
                        float v = acc[qm * 4 + mi][qn * 2 + nj][r] + bvv;
                        if (GELU) v = gelu_tanh(v);
                        size_t idx = (size_t)e * Mpe * N + (size_t)(m0 + row) * N + (n0 + col);
                        if (DUALOUT && flag) ((float*)Cout)[idx] = v;
                        else                 ((ushort_t*)Cout)[idx] = f2b(v);
                    }
                }
            }
        }
    }
}

extern "C" void kernel_launch(void* const* d_in, const int* in_sizes, int n_in,
                              void* d_out, int out_size, void* d_ws, size_t ws_size,
                              hipStream_t stream) {
    const void* x  = d_in[0];
    // d_in[1] = expert_size (uniform T/E by construction, unused)
    const void* w1 = d_in[2];
    const void* b1 = d_in[3];
    const void* w2 = d_in[4];
    const void* b2 = d_in[5];

    char* ws = (char*)d_ws;
    int*      flag = (int*)ws;                                    // @0
    ushort_t* xb   = (ushort_t*)(ws + ((size_t)1  << 20));        // 32 MB
    ushort_t* b1b  = (ushort_t*)(ws + ((size_t)34 << 20));        // 64 KB
    ushort_t* b2b  = (ushort_t*)(ws + ((size_t)35 << 20));        // 16 KB
    ushort_t* wT   = (ushort_t*)(ws + ((size_t)36 << 20));        // 64 MB (w1t, then w2t)
    ushort_t* H    = (ushort_t*)(ws + ((size_t)100 << 20));       // 128 MB -> ends 228 MB

    detect_dtype<<<1, 64, 0, stream>>>((const ushort_t*)x, flag);

    conv_bf16<<<(NT * ND / 8 + 255) / 256, 256, 0, stream>>>(x,  xb,  NT * ND, flag);
    conv_bf16<<<(NE * NF / 8 + 255) / 256, 256, 0, stream>>>(b1, b1b, NE * NF, flag);
    conv_bf16<<<(NE * ND / 8 + 255) / 256, 256, 0, stream>>>(b2, b2b, NE * ND, flag);

    // w1 [E][D][F] -> wT [E][F][D]
    transpose_e<<<dim3(NF / 64, ND / 64, NE), 256, 0, stream>>>(w1, wT, ND, NF, flag);
    // H = gelu(X @ W1 + b1)  — CONTROL ARM: round-2-verified gemm_bt8
    gemm_bt8<1, 0><<<dim3(NF / 256, MPE / 256, NE), 512, 0, stream>>>(
        xb, wT, b1b, H, MPE, NF, ND, flag);
    // w2 [E][F][D] -> wT [E][D][F]   (reuses wT after gemm1 is done)
    transpose_e<<<dim3(ND / 64, NF / 64, NE), 256, 0, stream>>>(w2, wT, NF, ND, flag);
    // Y = H @ W2 + b2  — TEST ARM: gemm_g2 (Gray schedule) under bisect
    gemm_g2<0, 1><<<dim3(ND / 256, MPE / 256, NE), 512, 0, stream>>>(
        H, wT, b2b, d_out, MPE, ND, NF, flag);
}